// Round 3
// baseline (346.314 us; speedup 1.0000x reference)
//
#include <hip/hip_runtime.h>
#include <cstdint>

// Problem constants (fixed by reference setup_inputs):
//   N = 200000, M = 64, D = 256, K = 3
#define D_DIM 256
#define M_DIM 64
#define K_TOP 3

typedef unsigned long long u64;
typedef int   v4i __attribute__((ext_vector_type(4)));
typedef float v4f __attribute__((ext_vector_type(4)));

// Kernel 1: per-node dual dot product. Persistent grid-stride; 4 rows per
// wave (16-lane teams). Lane p only ever needs W float4s {p,16+p,32+p,48+p}
// for both halves -> preload 8 float4 (32 VGPRs) ONCE, reuse for all rows.
// Per 4 rows: 4 VMEM insts (nf only, perfectly coalesced) vs 12 before.
__global__ __launch_bounds__(256) void ns_scores_kernel(
    const float* __restrict__ nf,      // (N, 256)
    const float* __restrict__ W,       // (512,)
    const float* __restrict__ b,       // (1,)
    float* __restrict__ s_self,        // (N,)
    float* __restrict__ s_all,         // (N,)
    int N)
{
    const int lane = threadIdx.x & 63;
    const int sub  = lane >> 4;        // team (row slot) within wave
    const int p    = lane & 15;        // lane within 16-lane team

    // Preload W fragments for this lane position (register-resident).
    const v4f* __restrict__ wa4 = (const v4f*)W;
    const v4f* __restrict__ wb4 = (const v4f*)(W + D_DIM);
    v4f wa[4], wb[4];
    #pragma unroll
    for (int i = 0; i < 4; ++i) {
        wa[i] = wa4[i * 16 + p];
        wb[i] = wb4[i * 16 + p];
    }
    const float bias = b[0];

    const int wave       = (blockIdx.x * blockDim.x + threadIdx.x) >> 6;
    const int totalWaves = (gridDim.x * blockDim.x) >> 6;

    for (int row = wave * 4 + sub; row < N; row += totalWaves * 4) {
        const v4f* __restrict__ vrow = (const v4f*)(nf + (size_t)row * D_DIM);
        float sa = 0.0f, sb = 0.0f;
        #pragma unroll
        for (int i = 0; i < 4; ++i) {
            const v4f v = vrow[i * 16 + p];   // 16 contiguous float4 per team
            sa += v.x * wa[i].x + v.y * wa[i].y + v.z * wa[i].z + v.w * wa[i].w;
            sb += v.x * wb[i].x + v.y * wb[i].y + v.z * wb[i].z + v.w * wb[i].w;
        }
        #pragma unroll
        for (int off = 8; off > 0; off >>= 1) {
            sa += __shfl_xor(sa, off);
            sb += __shfl_xor(sb, off);
        }
        if (p == 0) {
            __builtin_nontemporal_store(sa + bias, s_self + row);
            __builtin_nontemporal_store(sb,        s_all  + row);
        }
    }
}

// Kernel 2: per-node score + top-3. 4 rows per wave; lane p holds the row's
// neighbors 4p..4p+3 via one int4 nontemporal load (streams bypass L2 so the
// 800 KB s_all gather table stays L2-resident). Tie-break matches
// jax.lax.top_k (equal value -> lower index): key packs
// (score_bits << 32) | (63 - j); valid scores exp(...) > 0, so zeroed score
// bits are a safe knockout sentinel.
__global__ __launch_bounds__(256) void ns_topk_kernel(
    const int* __restrict__ neighbors, // (N, 64) int32
    const int* __restrict__ counts,    // (N,)    int32
    const float* __restrict__ s_self,  // (N,)
    const float* __restrict__ s_all,   // (N,)
    float* __restrict__ out_vals,      // (N, 3)
    float* __restrict__ out_idx,       // (N, 3)  indices as float
    int N)
{
    const int wave = (blockIdx.x * blockDim.x + threadIdx.x) >> 6;
    const int lane = threadIdx.x & 63;
    const int sub  = lane >> 4;
    const int p    = lane & 15;
    const int row  = wave * 4 + sub;
    if (row >= N) return;

    const v4i nb = __builtin_nontemporal_load(
        (const v4i*)(neighbors + (size_t)row * M_DIM) + p);
    const int   cnt = __builtin_nontemporal_load(counts + row);
    const float ss  = __builtin_nontemporal_load(s_self + row);

    const int nbs[4] = { nb.x, nb.y, nb.z, nb.w };
    u64 key[4];
    #pragma unroll
    for (int e = 0; e < 4; ++e) {
        const int j = p * 4 + e;
        float score = 0.0f;
        if (j < cnt) {
            const float x  = ss + s_all[nbs[e]];   // gather: keep cached
            const float lr = (x >= 0.0f) ? x : 0.01f * x;
            score = expf(lr);
        }
        key[e] = ((u64)__float_as_uint(score) << 32) | (u64)(63 - j);
    }

    float vals[K_TOP];
    int   idxs[K_TOP];

    #pragma unroll
    for (int k = 0; k < K_TOP; ++k) {
        u64 m = key[0];
        if (key[1] > m) m = key[1];
        if (key[2] > m) m = key[2];
        if (key[3] > m) m = key[3];
        #pragma unroll
        for (int off = 8; off > 0; off >>= 1) {
            const u64 o = __shfl_xor(m, off);
            if (o > m) m = o;
        }
        const int jwin = 63 - (int)(m & 0x3F);
        vals[k] = __uint_as_float((unsigned)(m >> 32));

        const int ew = jwin & 3;       // element within owner's int4
        const int pw = jwin >> 2;      // owner lane within team
        const int cand = (ew == 0) ? nbs[0] : (ew == 1) ? nbs[1]
                       : (ew == 2) ? nbs[2] : nbs[3];
        idxs[k] = __shfl(cand, (sub << 4) | pw);

        if (p == pw) {                 // owner knocks out the winning element
            const u64 dead = (u64)(63 - jwin);
            if      (ew == 0) key[0] = dead;
            else if (ew == 1) key[1] = dead;
            else if (ew == 2) key[2] = dead;
            else              key[3] = dead;
        }
    }

    if (p == 0) {
        const size_t base = (size_t)row * K_TOP;
        #pragma unroll
        for (int k = 0; k < K_TOP; ++k) {
            __builtin_nontemporal_store(vals[k],        out_vals + base + k);
            __builtin_nontemporal_store((float)idxs[k], out_idx  + base + k);
        }
    }
}

extern "C" void kernel_launch(void* const* d_in, const int* in_sizes, int n_in,
                              void* d_out, int out_size, void* d_ws, size_t ws_size,
                              hipStream_t stream)
{
    const float* nf        = (const float*)d_in[0];   // (N, 256)
    const int*   neighbors = (const int*)  d_in[1];   // (N, 64)
    const int*   counts    = (const int*)  d_in[2];   // (N,)
    const float* W         = (const float*)d_in[3];   // (512,)
    const float* b         = (const float*)d_in[4];   // (1,)

    const int N = in_sizes[2];

    float* s_self = (float*)d_ws;                     // N floats
    float* s_all  = s_self + N;                       // N floats

    float* out_vals = (float*)d_out;                  // N*3
    float* out_idx  = out_vals + (size_t)N * K_TOP;   // N*3 (indices as float)

    const int threads = 256;

    // k1: persistent grid-stride; 2048 blocks = 8 blocks/CU, W preloaded once.
    const int k1_blocks = 2048;
    ns_scores_kernel<<<k1_blocks, threads, 0, stream>>>(nf, W, b, s_self, s_all, N);

    // k2: one 16-lane team per row.
    const int rowsPerBlock = (threads / 64) * 4;
    const int k2_blocks = (N + rowsPerBlock - 1) / rowsPerBlock;
    ns_topk_kernel<<<k2_blocks, threads, 0, stream>>>(neighbors, counts, s_self, s_all,
                                                      out_vals, out_idx, N);
}

// Round 4
// 337.616 us; speedup vs baseline: 1.0258x; 1.0258x over previous
//
#include <hip/hip_runtime.h>
#include <cstdint>

// Problem constants (fixed by reference setup_inputs):
//   N = 200000, M = 64, D = 256, K = 3
#define D_DIM 256
#define M_DIM 64
#define K_TOP 3

typedef unsigned long long u64;
typedef int   v4i __attribute__((ext_vector_type(4)));
typedef float v4f __attribute__((ext_vector_type(4)));

// Kernel 1: per-node dual dot product. 4 rows per wave, 16 lanes per row.
// Lane loads 4x float4 (64B of the 1KB row); W re-read per wave is an L1
// hit and free against the ~400cy/wave HBM budget (persistent+preload
// variant measured neutral-to-worse in R3). Plain stores keep s_all
// resident in L2/L3 for k2's gathers.
__global__ __launch_bounds__(256) void ns_scores_kernel(
    const float* __restrict__ nf,      // (N, 256)
    const float* __restrict__ W,       // (512,)
    const float* __restrict__ b,       // (1,)
    float* __restrict__ s_self,        // (N,)
    float* __restrict__ s_all,         // (N,)
    int N)
{
    const int wave = (blockIdx.x * blockDim.x + threadIdx.x) >> 6;
    const int lane = threadIdx.x & 63;
    const int sub  = lane >> 4;        // row slot within wave
    const int p    = lane & 15;        // lane within 16-lane team
    const int row  = wave * 4 + sub;
    if (row >= N) return;

    const v4f* __restrict__ vrow = (const v4f*)(nf + (size_t)row * D_DIM);
    const v4f* __restrict__ wa4  = (const v4f*)W;
    const v4f* __restrict__ wb4  = (const v4f*)(W + D_DIM);

    float sa = 0.0f, sb = 0.0f;
    #pragma unroll
    for (int i = 0; i < 4; ++i) {
        const int o = i * 16 + p;
        const v4f v = vrow[o];
        const v4f a = wa4[o];
        const v4f c = wb4[o];
        sa += v.x * a.x + v.y * a.y + v.z * a.z + v.w * a.w;
        sb += v.x * c.x + v.y * c.y + v.z * c.z + v.w * c.w;
    }
    #pragma unroll
    for (int off = 8; off > 0; off >>= 1) {
        sa += __shfl_xor(sa, off);
        sb += __shfl_xor(sb, off);
    }
    if (p == 0) {
        s_self[row] = sa + b[0];
        s_all[row]  = sb;
    }
}

// Kernel 2: per-node score + top-3. 4 rows per wave; lane p owns neighbors
// 4p..4p+3 (one int4). counts ~ U[3,63] (mean 33) -> guard the int4 LOAD by
// 4p < cnt: masked lanes issue no memory request, halving neighbor HBM
// traffic (~51 -> ~26 MB). Neighbor stream is nontemporal so it doesn't
// evict the 800 KB s_all gather table from L2. Tie-break matches
// jax.lax.top_k (equal value -> lower index): key = (score_bits<<32)|(63-j);
// valid scores exp(...) > 0 so zeroed score bits are a safe knockout.
__global__ __launch_bounds__(256) void ns_topk_kernel(
    const int* __restrict__ neighbors, // (N, 64) int32
    const int* __restrict__ counts,    // (N,)    int32
    const float* __restrict__ s_self,  // (N,)
    const float* __restrict__ s_all,   // (N,)
    float* __restrict__ out_vals,      // (N, 3)
    float* __restrict__ out_idx,       // (N, 3)  indices as float
    int N)
{
    const int wave = (blockIdx.x * blockDim.x + threadIdx.x) >> 6;
    const int lane = threadIdx.x & 63;
    const int sub  = lane >> 4;
    const int p    = lane & 15;
    const int row  = wave * 4 + sub;
    if (row >= N) return;

    const int   cnt = counts[row];     // uniform in team -> broadcast line
    const float ss  = s_self[row];

    v4i nb = (v4i){0, 0, 0, 0};
    if (p * 4 < cnt) {                 // skip fully-masked int4s entirely
        nb = __builtin_nontemporal_load(
            (const v4i*)(neighbors + (size_t)row * M_DIM) + p);
    }

    const int nbs[4] = { nb.x, nb.y, nb.z, nb.w };
    u64 key[4];
    #pragma unroll
    for (int e = 0; e < 4; ++e) {
        const int j = p * 4 + e;
        float score = 0.0f;
        if (j < cnt) {
            const float x  = ss + s_all[nbs[e]];   // L2-resident gather
            const float lr = (x >= 0.0f) ? x : 0.01f * x;
            score = expf(lr);
        }
        key[e] = ((u64)__float_as_uint(score) << 32) | (u64)(63 - j);
    }

    float vals[K_TOP];
    int   idxs[K_TOP];

    #pragma unroll
    for (int k = 0; k < K_TOP; ++k) {
        u64 m = key[0];
        if (key[1] > m) m = key[1];
        if (key[2] > m) m = key[2];
        if (key[3] > m) m = key[3];
        #pragma unroll
        for (int off = 8; off > 0; off >>= 1) {
            const u64 o = __shfl_xor(m, off);
            if (o > m) m = o;
        }
        const int jwin = 63 - (int)(m & 0x3F);
        vals[k] = __uint_as_float((unsigned)(m >> 32));

        const int ew = jwin & 3;       // element within owner's int4
        const int pw = jwin >> 2;      // owner lane within team
        const int cand = (ew == 0) ? nbs[0] : (ew == 1) ? nbs[1]
                       : (ew == 2) ? nbs[2] : nbs[3];
        idxs[k] = __shfl(cand, (sub << 4) | pw);   // owner was active (jwin<cnt)

        if (p == pw) {                 // owner knocks out the winning element
            const u64 dead = (u64)(63 - jwin);
            if      (ew == 0) key[0] = dead;
            else if (ew == 1) key[1] = dead;
            else if (ew == 2) key[2] = dead;
            else              key[3] = dead;
        }
    }

    if (p == 0) {
        const size_t base = (size_t)row * K_TOP;
        #pragma unroll
        for (int k = 0; k < K_TOP; ++k) {
            out_vals[base + k] = vals[k];
            out_idx [base + k] = (float)idxs[k];
        }
    }
}

extern "C" void kernel_launch(void* const* d_in, const int* in_sizes, int n_in,
                              void* d_out, int out_size, void* d_ws, size_t ws_size,
                              hipStream_t stream)
{
    const float* nf        = (const float*)d_in[0];   // (N, 256)
    const int*   neighbors = (const int*)  d_in[1];   // (N, 64)
    const int*   counts    = (const int*)  d_in[2];   // (N,)
    const float* W         = (const float*)d_in[3];   // (512,)
    const float* b         = (const float*)d_in[4];   // (1,)

    const int N = in_sizes[2];

    float* s_self = (float*)d_ws;                     // N floats
    float* s_all  = s_self + N;                       // N floats

    float* out_vals = (float*)d_out;                  // N*3
    float* out_idx  = out_vals + (size_t)N * K_TOP;   // N*3 (indices as float)

    const int threads = 256;                          // 4 waves -> 16 rows/block
    const int rowsPerBlock = (threads / 64) * 4;
    const int blocks = (N + rowsPerBlock - 1) / rowsPerBlock;

    ns_scores_kernel<<<blocks, threads, 0, stream>>>(nf, W, b, s_self, s_all, N);
    ns_topk_kernel<<<blocks, threads, 0, stream>>>(neighbors, counts, s_self, s_all,
                                                   out_vals, out_idx, N);
}